// Round 2
// baseline (423.224 us; speedup 1.0000x reference)
//
#include <hip/hip_runtime.h>
#include <hip/hip_bf16.h>
#include <hip/hip_fp16.h>
#include <math.h>

#define BATCH 64
#define LAT   256
#define DVOX  64
#define VOX   (DVOX*DVOX*DVOX)   // 262144

typedef __attribute__((ext_vector_type(8))) short short8;
typedef __attribute__((ext_vector_type(4))) float f32x4;

// ---------------- kernel 0: enc -> bf16, build rotation matrices -----------
__global__ void prep_kernel(const float* __restrict__ enc,      // [64,256]
                            const float* __restrict__ angles,   // [64,3]
                            unsigned short* __restrict__ encB,  // [64,256] bf16 bits
                            float* __restrict__ Rmat) {         // [64,9]
    int tid = threadIdx.x;
    for (int idx = tid; idx < BATCH * LAT; idx += blockDim.x) {
        __hip_bfloat16 h = __float2bfloat16(enc[idx]);
        encB[idx] = *reinterpret_cast<unsigned short*>(&h);
    }
    if (tid < BATCH) {
        float ax = angles[tid*3+0], ay = angles[tid*3+1], az = angles[tid*3+2];
        float cx = cosf(ax), sx = sinf(ax);
        float cy = cosf(ay), sy = sinf(ay);
        float cz = cosf(az), sz = sinf(az);
        float* R = Rmat + tid * 9;
        // R = Rz @ Ry @ Rx
        R[0] = cz*cy;  R[1] = cz*sy*sx - sz*cx;  R[2] = cz*sy*cx + sz*sx;
        R[3] = sz*cy;  R[4] = sz*sy*sx + cz*cx;  R[5] = sz*sy*cx - cz*sx;
        R[6] = -sy;    R[7] = cy*sx;             R[8] = cy*cx;
    }
}

// ---------------- kernel 1: MFMA GEMM + sigmoid^8 -> fp16 voxels -----------
// C = enc @ W : M=64 (batch), K=256, N=262144 (voxel).
// Per wave: 64x16 output tile via 4x mfma_f32_16x16x32_bf16 per K-step.
// A-frag: lane holds enc[mt*16 + (l&15)][kb + (l>>4)*8 + j], j=0..7 (contig bf16x8).
// B-frag: lane holds W[kb + (l>>4)*8 + j][n0 + (l&15)] (fp32 -> bf16 cvt);
//         each dword load = 16 consecutive n * 4 k-rows -> full 64B line use.
// C/D: col = l&15 (voxel), row = (l>>4)*4 + r + mt*16 (batch)  [verified map].
__global__ __launch_bounds__(256) void gemm_mfma_kernel(
        const unsigned short* __restrict__ encB,  // [64,256] bf16
        const float* __restrict__ W,              // [256, 262144]
        const float* __restrict__ bias,           // [262144]
        __half* __restrict__ vox) {               // [64, 262144] fp16
    int wave = threadIdx.x >> 6;
    int lane = threadIdx.x & 63;
    int l15 = lane & 15, l4 = lane >> 4;
    int n0 = blockIdx.x * 64 + wave * 16;
    int n = n0 + l15;

    f32x4 acc[4];
#pragma unroll
    for (int mt = 0; mt < 4; ++mt) acc[mt] = (f32x4){0.f, 0.f, 0.f, 0.f};

    const unsigned short* ap = encB + l15 * LAT + l4 * 8;
    const float* wp = W + (size_t)(l4 * 8) * VOX + n;

    for (int kb = 0; kb < LAT; kb += 32) {
        short8 a0 = *(const short8*)(ap + 0 * 16 * LAT + kb);
        short8 a1 = *(const short8*)(ap + 1 * 16 * LAT + kb);
        short8 a2 = *(const short8*)(ap + 2 * 16 * LAT + kb);
        short8 a3 = *(const short8*)(ap + 3 * 16 * LAT + kb);
        const float* w = wp + (size_t)kb * VOX;
        short8 bf;
#pragma unroll
        for (int j = 0; j < 8; ++j) {
            __hip_bfloat16 h = __float2bfloat16(w[(size_t)j * VOX]);
            bf[j] = *reinterpret_cast<short*>(&h);
        }
        acc[0] = __builtin_amdgcn_mfma_f32_16x16x32_bf16(a0, bf, acc[0], 0, 0, 0);
        acc[1] = __builtin_amdgcn_mfma_f32_16x16x32_bf16(a1, bf, acc[1], 0, 0, 0);
        acc[2] = __builtin_amdgcn_mfma_f32_16x16x32_bf16(a2, bf, acc[2], 0, 0, 0);
        acc[3] = __builtin_amdgcn_mfma_f32_16x16x32_bf16(a3, bf, acc[3], 0, 0, 0);
    }

    float bv = bias[n];   // all 16 C-elements of this lane share column n
#pragma unroll
    for (int mt = 0; mt < 4; ++mt) {
#pragma unroll
        for (int r = 0; r < 4; ++r) {
            int b = mt * 16 + l4 * 4 + r;
            float x = acc[mt][r] + bv;
            float s = 1.f / (1.f + __expf(-x));   // sigmoid
            s = s * s; s = s * s; s = s * s;      // ^8
            vox[(size_t)b * VOX + n] = __float2half(s);
        }
    }
}

// ---------------- kernel 2: rotate-resample + alpha composite --------------
__device__ __forceinline__ float gath(const __half* __restrict__ V,
                                      int ix, int iy, int iz) {
    if ((unsigned)ix < (unsigned)DVOX &&
        (unsigned)iy < (unsigned)DVOX &&
        (unsigned)iz < (unsigned)DVOX)
        return __half2float(V[(ix << 12) + (iy << 6) + iz]);
    return 0.f;
}

// block = 256 thr = 4 depth-chunks (waves) x 64 pixels (8x8 tile).
// Each (pixel,chunk) computes segment transmittance T and emission E over 16
// z-steps; LDS combine: img = E0 + T0*(E1 + T1*(E2 + T2*E3)).
// blockIdx = tile*64 + b  ->  blockIdx%8 == b%8 (same-batch blocks share XCD L2).
__global__ __launch_bounds__(256) void render_kernel(
        const __half* __restrict__ vox,   // [64, 262144] fp16
        const float* __restrict__ Rmat,   // [64,9]
        float* __restrict__ out) {        // [64,1,64,64]
    int bid  = blockIdx.x;
    int b    = bid & 63;
    int tile = bid >> 6;                  // 0..63: 8x8 tiles of 8x8 pixels
    int ti = tile >> 3, tj = tile & 7;
    int tid = threadIdx.x;
    int pix = tid & 63, chunk = tid >> 6; // wave == chunk (uniform k-range)
    int li = pix >> 3, lj = pix & 7;
    int i = ti * 8 + li;
    int j = tj * 8 + lj;

    const float* Rb = Rmat + b * 9;       // wave-uniform -> scalar loads
    float R0 = Rb[0], R1 = Rb[1], R2 = Rb[2];
    float R3 = Rb[3], R4 = Rb[4], R5 = Rb[5];
    float R6 = Rb[6], R7 = Rb[7], R8 = Rb[8];

    const float c = (DVOX - 1) * 0.5f;    // 31.5
    float di = (float)i - c, dj = (float)j - c;
    float xb = fmaf(R0, di, fmaf(R1, dj, c));
    float yb = fmaf(R3, di, fmaf(R4, dj, c));
    float zb = fmaf(R6, di, fmaf(R7, dj, c));

    const __half* V = vox + (size_t)b * VOX;

    float T = 1.f, E = 0.f;
    int k0 = chunk * 16;
#pragma unroll 4
    for (int kk = 15; kk >= 0; --kk) {    // back-to-front within chunk
        float dk = (float)(k0 + kk) - c;
        float x = fmaf(R2, dk, xb);
        float y = fmaf(R5, dk, yb);
        float z = fmaf(R8, dk, zb);

        float x0f = floorf(x), y0f = floorf(y), z0f = floorf(z);
        int x0 = (int)x0f, y0 = (int)y0f, z0 = (int)z0f;
        float fx = x - x0f, fy = y - y0f, fz = z - z0f;

        float c000 = gath(V, x0,     y0,     z0);
        float c001 = gath(V, x0,     y0,     z0 + 1);
        float c010 = gath(V, x0,     y0 + 1, z0);
        float c011 = gath(V, x0,     y0 + 1, z0 + 1);
        float c100 = gath(V, x0 + 1, y0,     z0);
        float c101 = gath(V, x0 + 1, y0,     z0 + 1);
        float c110 = gath(V, x0 + 1, y0 + 1, z0);
        float c111 = gath(V, x0 + 1, y0 + 1, z0 + 1);

        float c00 = c000 + (c001 - c000) * fz;
        float c01 = c010 + (c011 - c010) * fz;
        float c10 = c100 + (c101 - c100) * fz;
        float c11 = c110 + (c111 - c110) * fz;
        float c0  = c00 + (c01 - c00) * fy;
        float c1  = c10 + (c11 - c10) * fy;
        float a   = c0  + (c1  - c0 ) * fx;

        E = E * (1.f - a) + a;
        T *= (1.f - a);
    }

    __shared__ float sT[4][64], sE[4][64];
    sT[chunk][pix] = T;
    sE[chunk][pix] = E;
    __syncthreads();

    if (chunk == 0) {
        float img = sE[3][pix];
        img = fmaf(sT[2][pix], img, sE[2][pix]);
        img = fmaf(sT[1][pix], img, sE[1][pix]);
        img = fmaf(T, img, E);            // chunk 0's own registers
        out[b * (DVOX * DVOX) + i * DVOX + j] = 2.f * img - 1.f;
    }
}

// ---------------------------------------------------------------------------
extern "C" void kernel_launch(void* const* d_in, const int* in_sizes, int n_in,
                              void* d_out, int out_size, void* d_ws, size_t ws_size,
                              hipStream_t stream) {
    const float* enc    = (const float*)d_in[0];   // [64,256]
    const float* W      = (const float*)d_in[1];   // [256,262144]
    const float* bias   = (const float*)d_in[2];   // [262144]
    const float* angles = (const float*)d_in[3];   // [64,3]
    float* out = (float*)d_out;

    char* ws = (char*)d_ws;
    unsigned short* encB = (unsigned short*)ws;          // 32 KB
    float* Rmat          = (float*)(ws + 32768);         // 2.3 KB
    __half* vox          = (__half*)(ws + 65536);        // 32 MB

    prep_kernel<<<1, 256, 0, stream>>>(enc, angles, encB, Rmat);
    gemm_mfma_kernel<<<VOX / 64, 256, 0, stream>>>(encB, W, bias, vox);
    render_kernel<<<BATCH * 64, 256, 0, stream>>>(vox, Rmat, out);
}

// Round 3
// 356.081 us; speedup vs baseline: 1.1886x; 1.1886x over previous
//
#include <hip/hip_runtime.h>
#include <hip/hip_bf16.h>
#include <hip/hip_fp16.h>
#include <math.h>

#define BATCH 64
#define LAT   256
#define DVOX  64
#define VOX   (DVOX*DVOX*DVOX)   // 262144
#define P65   65
#define PBATCH (P65*P65*P65)     // 274625 entries per batch (uint4 each)

typedef __attribute__((ext_vector_type(8))) short short8;
typedef __attribute__((ext_vector_type(4))) float f32x4;

// ---------------- kernel 0: enc -> bf16, build rotation matrices -----------
__global__ void prep_kernel(const float* __restrict__ enc,      // [64,256]
                            const float* __restrict__ angles,   // [64,3]
                            unsigned short* __restrict__ encB,  // [64,256] bf16 bits
                            float* __restrict__ Rmat) {         // [64,9]
    int tid = threadIdx.x;
    for (int idx = tid; idx < BATCH * LAT; idx += blockDim.x) {
        __hip_bfloat16 h = __float2bfloat16(enc[idx]);
        encB[idx] = *reinterpret_cast<unsigned short*>(&h);
    }
    if (tid < BATCH) {
        float ax = angles[tid*3+0], ay = angles[tid*3+1], az = angles[tid*3+2];
        float cx = cosf(ax), sx = sinf(ax);
        float cy = cosf(ay), sy = sinf(ay);
        float cz = cosf(az), sz = sinf(az);
        float* R = Rmat + tid * 9;
        R[0] = cz*cy;  R[1] = cz*sy*sx - sz*cx;  R[2] = cz*sy*cx + sz*sx;
        R[3] = sz*cy;  R[4] = sz*sy*sx + cz*cx;  R[5] = sz*sy*cx - cz*sx;
        R[6] = -sy;    R[7] = cy*sx;             R[8] = cy*cx;
    }
}

// ---------------- kernel 1: MFMA GEMM + sigmoid^8 -> fp16 voxels -----------
__global__ __launch_bounds__(256) void gemm_mfma_kernel(
        const unsigned short* __restrict__ encB,  // [64,256] bf16
        const float* __restrict__ W,              // [256, 262144]
        const float* __restrict__ bias,           // [262144]
        __half* __restrict__ vox) {               // [64, 262144] fp16
    int wave = threadIdx.x >> 6;
    int lane = threadIdx.x & 63;
    int l15 = lane & 15, l4 = lane >> 4;
    int n0 = blockIdx.x * 64 + wave * 16;
    int n = n0 + l15;

    f32x4 acc[4];
#pragma unroll
    for (int mt = 0; mt < 4; ++mt) acc[mt] = (f32x4){0.f, 0.f, 0.f, 0.f};

    const unsigned short* ap = encB + l15 * LAT + l4 * 8;
    const float* wp = W + (size_t)(l4 * 8) * VOX + n;

    for (int kb = 0; kb < LAT; kb += 32) {
        short8 a0 = *(const short8*)(ap + 0 * 16 * LAT + kb);
        short8 a1 = *(const short8*)(ap + 1 * 16 * LAT + kb);
        short8 a2 = *(const short8*)(ap + 2 * 16 * LAT + kb);
        short8 a3 = *(const short8*)(ap + 3 * 16 * LAT + kb);
        const float* w = wp + (size_t)kb * VOX;
        short8 bf;
#pragma unroll
        for (int j = 0; j < 8; ++j) {
            __hip_bfloat16 h = __float2bfloat16(w[(size_t)j * VOX]);
            bf[j] = *reinterpret_cast<short*>(&h);
        }
        acc[0] = __builtin_amdgcn_mfma_f32_16x16x32_bf16(a0, bf, acc[0], 0, 0, 0);
        acc[1] = __builtin_amdgcn_mfma_f32_16x16x32_bf16(a1, bf, acc[1], 0, 0, 0);
        acc[2] = __builtin_amdgcn_mfma_f32_16x16x32_bf16(a2, bf, acc[2], 0, 0, 0);
        acc[3] = __builtin_amdgcn_mfma_f32_16x16x32_bf16(a3, bf, acc[3], 0, 0, 0);
    }

    float bv = bias[n];
#pragma unroll
    for (int mt = 0; mt < 4; ++mt) {
#pragma unroll
        for (int r = 0; r < 4; ++r) {
            int b = mt * 16 + l4 * 4 + r;
            float x = acc[mt][r] + bv;
            float s = 1.f / (1.f + __expf(-x));   // sigmoid
            s = s * s; s = s * s; s = s * s;      // ^8
            vox[(size_t)b * VOX + n] = __float2half(s);
        }
    }
}

// ---------------- kernel 1.5: pack 8 trilinear corners per cell ------------
// vox8[b][xi][yi][zi] (65^3, uint4) holds corners V[x0+dx,y0+dy,z0+dz]
// (x0=xi-1 etc.), with 0 for out-of-range corners. Layout: halves
// h[dx*4+dy*2+dz]; word w = dx*2+dy packs (dz=0 | dz=1<<16).
__global__ __launch_bounds__(256) void pack_kernel(
        const __half* __restrict__ vox,   // [64, 262144]
        uint4* __restrict__ vox8) {       // [64, 65^3]
    int xi = blockIdx.x % P65;
    int b  = blockIdx.x / P65;
    int x0 = xi - 1;
    const unsigned short* V = (const unsigned short*)(vox + (size_t)b * VOX);
    uint4* out = vox8 + (size_t)b * PBATCH + (size_t)xi * (P65 * P65);

    for (int idx = threadIdx.x; idx < P65 * P65; idx += 256) {
        int yi = idx / P65;
        int zi = idx - yi * P65;
        int y0 = yi - 1, z0 = zi - 1;
        unsigned w[4];
#pragma unroll
        for (int dx = 0; dx < 2; ++dx) {
#pragma unroll
            for (int dy = 0; dy < 2; ++dy) {
                int xs = x0 + dx, ys = y0 + dy;
                bool rv = ((unsigned)xs < DVOX) & ((unsigned)ys < DVOX);
                int base = (xs << 12) + (ys << 6);
                unsigned lo = (rv && z0 >= 0)       ? (unsigned)V[base + z0]     : 0u;
                unsigned hi = (rv && z0 + 1 < DVOX) ? (unsigned)V[base + z0 + 1] : 0u;
                w[dx * 2 + dy] = lo | (hi << 16);
            }
        }
        out[idx] = make_uint4(w[0], w[1], w[2], w[3]);
    }
}

// ---------------- kernel 2: rotate-resample + composite (packed gather) ----
__global__ __launch_bounds__(256) void render8_kernel(
        const uint4* __restrict__ vox8,   // [64, 65^3]
        const float* __restrict__ Rmat,   // [64,9]
        float* __restrict__ out) {        // [64,1,64,64]
    int bid  = blockIdx.x;
    int b    = bid & 63;
    int tile = bid >> 6;                  // 0..63: 8x8 tiles of 8x8 pixels
    int ti = tile >> 3, tj = tile & 7;
    int tid = threadIdx.x;
    int pix = tid & 63, chunk = tid >> 6;
    int li = pix >> 3, lj = pix & 7;
    int i = ti * 8 + li;
    int j = tj * 8 + lj;

    const float* Rb = Rmat + b * 9;
    float R0 = Rb[0], R1 = Rb[1], R2 = Rb[2];
    float R3 = Rb[3], R4 = Rb[4], R5 = Rb[5];
    float R6 = Rb[6], R7 = Rb[7], R8 = Rb[8];

    const float c = (DVOX - 1) * 0.5f;
    float di = (float)i - c, dj = (float)j - c;
    float xb = fmaf(R0, di, fmaf(R1, dj, c));
    float yb = fmaf(R3, di, fmaf(R4, dj, c));
    float zb = fmaf(R6, di, fmaf(R7, dj, c));

    const uint4* V8 = vox8 + (size_t)b * PBATCH;

    float T = 1.f, E = 0.f;
    int k0 = chunk * 16;
#pragma unroll 4
    for (int kk = 15; kk >= 0; --kk) {    // back-to-front within chunk
        float dk = (float)(k0 + kk) - c;
        float x = fmaf(R2, dk, xb);
        float y = fmaf(R5, dk, yb);
        float z = fmaf(R8, dk, zb);

        float xf = floorf(x), yf = floorf(y), zf = floorf(z);
        float fx = x - xf, fy = y - yf, fz = z - zf;
        int xi = (int)xf + 1, yi = (int)yf + 1, zi = (int)zf + 1;
        bool valid = ((unsigned)xi < (unsigned)P65) &
                     ((unsigned)yi < (unsigned)P65) &
                     ((unsigned)zi < (unsigned)P65);
        int xc = min(max(xi, 0), P65 - 1);
        int yc = min(max(yi, 0), P65 - 1);
        int zc = min(max(zi, 0), P65 - 1);

        uint4 q = V8[xc * (P65 * P65) + yc * P65 + zc];
        float2 f00 = __half22float2(*reinterpret_cast<__half2*>(&q.x)); // x0,y0: z0,z1
        float2 f01 = __half22float2(*reinterpret_cast<__half2*>(&q.y)); // x0,y1
        float2 f10 = __half22float2(*reinterpret_cast<__half2*>(&q.z)); // x1,y0
        float2 f11 = __half22float2(*reinterpret_cast<__half2*>(&q.w)); // x1,y1

        float c00 = f00.x + (f00.y - f00.x) * fz;
        float c01 = f01.x + (f01.y - f01.x) * fz;
        float c10 = f10.x + (f10.y - f10.x) * fz;
        float c11 = f11.x + (f11.y - f11.x) * fz;
        float c0  = c00 + (c01 - c00) * fy;
        float c1  = c10 + (c11 - c10) * fy;
        float a   = c0  + (c1  - c0 ) * fx;
        a = valid ? a : 0.f;

        E = E * (1.f - a) + a;
        T *= (1.f - a);
    }

    __shared__ float sT[4][64], sE[4][64];
    sT[chunk][pix] = T;
    sE[chunk][pix] = E;
    __syncthreads();

    if (chunk == 0) {
        float img = sE[3][pix];
        img = fmaf(sT[2][pix], img, sE[2][pix]);
        img = fmaf(sT[1][pix], img, sE[1][pix]);
        img = fmaf(T, img, E);
        out[b * (DVOX * DVOX) + i * DVOX + j] = 2.f * img - 1.f;
    }
}

// ---------------- fallback render (direct fp16 gathers) --------------------
__device__ __forceinline__ float gath(const __half* __restrict__ V,
                                      int ix, int iy, int iz) {
    if ((unsigned)ix < (unsigned)DVOX &&
        (unsigned)iy < (unsigned)DVOX &&
        (unsigned)iz < (unsigned)DVOX)
        return __half2float(V[(ix << 12) + (iy << 6) + iz]);
    return 0.f;
}

__global__ __launch_bounds__(256) void render_fb_kernel(
        const __half* __restrict__ vox,
        const float* __restrict__ Rmat,
        float* __restrict__ out) {
    int bid  = blockIdx.x;
    int b    = bid & 63;
    int tile = bid >> 6;
    int ti = tile >> 3, tj = tile & 7;
    int tid = threadIdx.x;
    int pix = tid & 63, chunk = tid >> 6;
    int li = pix >> 3, lj = pix & 7;
    int i = ti * 8 + li;
    int j = tj * 8 + lj;

    const float* Rb = Rmat + b * 9;
    float R0 = Rb[0], R1 = Rb[1], R2 = Rb[2];
    float R3 = Rb[3], R4 = Rb[4], R5 = Rb[5];
    float R6 = Rb[6], R7 = Rb[7], R8 = Rb[8];

    const float c = (DVOX - 1) * 0.5f;
    float di = (float)i - c, dj = (float)j - c;
    float xb = fmaf(R0, di, fmaf(R1, dj, c));
    float yb = fmaf(R3, di, fmaf(R4, dj, c));
    float zb = fmaf(R6, di, fmaf(R7, dj, c));

    const __half* V = vox + (size_t)b * VOX;

    float T = 1.f, E = 0.f;
    int k0 = chunk * 16;
    for (int kk = 15; kk >= 0; --kk) {
        float dk = (float)(k0 + kk) - c;
        float x = fmaf(R2, dk, xb);
        float y = fmaf(R5, dk, yb);
        float z = fmaf(R8, dk, zb);

        float x0f = floorf(x), y0f = floorf(y), z0f = floorf(z);
        int x0 = (int)x0f, y0 = (int)y0f, z0 = (int)z0f;
        float fx = x - x0f, fy = y - y0f, fz = z - z0f;

        float c000 = gath(V, x0, y0, z0),     c001 = gath(V, x0, y0, z0 + 1);
        float c010 = gath(V, x0, y0 + 1, z0), c011 = gath(V, x0, y0 + 1, z0 + 1);
        float c100 = gath(V, x0 + 1, y0, z0), c101 = gath(V, x0 + 1, y0, z0 + 1);
        float c110 = gath(V, x0 + 1, y0 + 1, z0), c111 = gath(V, x0 + 1, y0 + 1, z0 + 1);

        float c00 = c000 + (c001 - c000) * fz;
        float c01 = c010 + (c011 - c010) * fz;
        float c10 = c100 + (c101 - c100) * fz;
        float c11 = c110 + (c111 - c110) * fz;
        float c0  = c00 + (c01 - c00) * fy;
        float c1  = c10 + (c11 - c10) * fy;
        float a   = c0  + (c1  - c0 ) * fx;

        E = E * (1.f - a) + a;
        T *= (1.f - a);
    }

    __shared__ float sT[4][64], sE[4][64];
    sT[chunk][pix] = T;
    sE[chunk][pix] = E;
    __syncthreads();

    if (chunk == 0) {
        float img = sE[3][pix];
        img = fmaf(sT[2][pix], img, sE[2][pix]);
        img = fmaf(sT[1][pix], img, sE[1][pix]);
        img = fmaf(T, img, E);
        out[b * (DVOX * DVOX) + i * DVOX + j] = 2.f * img - 1.f;
    }
}

// ---------------------------------------------------------------------------
extern "C" void kernel_launch(void* const* d_in, const int* in_sizes, int n_in,
                              void* d_out, int out_size, void* d_ws, size_t ws_size,
                              hipStream_t stream) {
    const float* enc    = (const float*)d_in[0];
    const float* W      = (const float*)d_in[1];
    const float* bias   = (const float*)d_in[2];
    const float* angles = (const float*)d_in[3];
    float* out = (float*)d_out;

    char* ws = (char*)d_ws;
    unsigned short* encB = (unsigned short*)ws;           // 32 KB
    float* Rmat          = (float*)(ws + 32768);          // 2.3 KB
    __half* vox          = (__half*)(ws + 65536);         // 32 MiB
    size_t vox8_off      = 65536 + (size_t)BATCH * VOX * 2;
    uint4* vox8          = (uint4*)(ws + vox8_off);       // 268 MiB
    size_t need          = vox8_off + (size_t)BATCH * PBATCH * 16;

    prep_kernel<<<1, 256, 0, stream>>>(enc, angles, encB, Rmat);
    gemm_mfma_kernel<<<VOX / 64, 256, 0, stream>>>(encB, W, bias, vox);
    if (ws_size >= need) {
        pack_kernel<<<BATCH * P65, 256, 0, stream>>>(vox, vox8);
        render8_kernel<<<BATCH * 64, 256, 0, stream>>>(vox8, Rmat, out);
    } else {
        render_fb_kernel<<<BATCH * 64, 256, 0, stream>>>(vox, Rmat, out);
    }
}

// Round 4
// 355.714 us; speedup vs baseline: 1.1898x; 1.0010x over previous
//
#include <hip/hip_runtime.h>
#include <hip/hip_bf16.h>
#include <hip/hip_fp16.h>
#include <math.h>

#define BATCH 64
#define LAT   256
#define DVOX  64
#define VOX   (DVOX*DVOX*DVOX)   // 262144

typedef __attribute__((ext_vector_type(8))) short short8;
typedef __attribute__((ext_vector_type(4))) float f32x4;

// ---------------- kernel 0: enc -> bf16, build rotation matrices -----------
__global__ void prep_kernel(const float* __restrict__ enc,      // [64,256]
                            const float* __restrict__ angles,   // [64,3]
                            unsigned short* __restrict__ encB,  // [64,256] bf16 bits
                            float* __restrict__ Rmat) {         // [64,9]
    int tid = threadIdx.x;
    for (int idx = tid; idx < BATCH * LAT; idx += blockDim.x) {
        __hip_bfloat16 h = __float2bfloat16(enc[idx]);
        encB[idx] = *reinterpret_cast<unsigned short*>(&h);
    }
    if (tid < BATCH) {
        float ax = angles[tid*3+0], ay = angles[tid*3+1], az = angles[tid*3+2];
        float cx = cosf(ax), sx = sinf(ax);
        float cy = cosf(ay), sy = sinf(ay);
        float cz = cosf(az), sz = sinf(az);
        float* R = Rmat + tid * 9;
        R[0] = cz*cy;  R[1] = cz*sy*sx - sz*cx;  R[2] = cz*sy*cx + sz*sx;
        R[3] = sz*cy;  R[4] = sz*sy*sx + cz*cx;  R[5] = sz*sy*cx - cz*sx;
        R[6] = -sy;    R[7] = cy*sx;             R[8] = cy*cx;
    }
}

// ---------------- kernel 1: MFMA GEMM + sigmoid^8 -> fp16 voxels -----------
__global__ __launch_bounds__(256) void gemm_mfma_kernel(
        const unsigned short* __restrict__ encB,  // [64,256] bf16
        const float* __restrict__ W,              // [256, 262144]
        const float* __restrict__ bias,           // [262144]
        __half* __restrict__ vox) {               // [64, 262144] fp16
    int wave = threadIdx.x >> 6;
    int lane = threadIdx.x & 63;
    int l15 = lane & 15, l4 = lane >> 4;
    int n0 = blockIdx.x * 64 + wave * 16;
    int n = n0 + l15;

    f32x4 acc[4];
#pragma unroll
    for (int mt = 0; mt < 4; ++mt) acc[mt] = (f32x4){0.f, 0.f, 0.f, 0.f};

    const unsigned short* ap = encB + l15 * LAT + l4 * 8;
    const float* wp = W + (size_t)(l4 * 8) * VOX + n;

    for (int kb = 0; kb < LAT; kb += 32) {
        short8 a0 = *(const short8*)(ap + 0 * 16 * LAT + kb);
        short8 a1 = *(const short8*)(ap + 1 * 16 * LAT + kb);
        short8 a2 = *(const short8*)(ap + 2 * 16 * LAT + kb);
        short8 a3 = *(const short8*)(ap + 3 * 16 * LAT + kb);
        const float* w = wp + (size_t)kb * VOX;
        short8 bf;
#pragma unroll
        for (int j = 0; j < 8; ++j) {
            __hip_bfloat16 h = __float2bfloat16(w[(size_t)j * VOX]);
            bf[j] = *reinterpret_cast<short*>(&h);
        }
        acc[0] = __builtin_amdgcn_mfma_f32_16x16x32_bf16(a0, bf, acc[0], 0, 0, 0);
        acc[1] = __builtin_amdgcn_mfma_f32_16x16x32_bf16(a1, bf, acc[1], 0, 0, 0);
        acc[2] = __builtin_amdgcn_mfma_f32_16x16x32_bf16(a2, bf, acc[2], 0, 0, 0);
        acc[3] = __builtin_amdgcn_mfma_f32_16x16x32_bf16(a3, bf, acc[3], 0, 0, 0);
    }

    float bv = bias[n];
#pragma unroll
    for (int mt = 0; mt < 4; ++mt) {
#pragma unroll
        for (int r = 0; r < 4; ++r) {
            int b = mt * 16 + l4 * 4 + r;
            float x = acc[mt][r] + bv;
            float s = 1.f / (1.f + __expf(-x));   // sigmoid
            s = s * s; s = s * s; s = s * s;      // ^8
            vox[(size_t)b * VOX + n] = __float2half(s);
        }
    }
}

// ---------------- kernel 2: LDS-staged rotate-resample + composite ---------
// Block = 1 wave (64 thr) = one 8x8 pixel tile of one batch. Serial over 8
// z-chunks of 8 steps (back-to-front). Per chunk: the rotated sample bbox of
// the 8x8x8 (pixel,z) block has per-axis span <= 7*sqrt(3)+3 < 16 for ANY
// rotation, so a 16x16x16 brick of uint entries (fp16 pair V[z],V[z+1])
// staged from the L2-resident volume covers all samples. Entry addressing is
// idx = xi<<8 | yi<<4 | zi. Zero padding baked in -> no bounds checks in the
// sample loop; each sample = 4 ds_read_b32 + trilinear + composite.
__device__ __forceinline__ float zlerp(unsigned e, float fz) {
    __half2 h = *reinterpret_cast<__half2*>(&e);
    float2 f = __half22float2(h);
    return f.x + (f.y - f.x) * fz;
}

__global__ __launch_bounds__(64) void render_lds_kernel(
        const __half* __restrict__ vox,   // [64, 262144] fp16
        const float* __restrict__ Rmat,   // [64,9]
        float* __restrict__ out) {        // [64,1,64,64]
    __shared__ unsigned sV[4096];         // 16 KB brick

    int bid  = blockIdx.x;
    int b    = bid & 63;                  // bid%8 == b%8 -> XCD affinity
    int tile = bid >> 6;                  // 0..63
    int l    = threadIdx.x;
    int i0 = (tile >> 3) * 8, j0 = (tile & 7) * 8;
    int i = i0 + (l >> 3);
    int j = j0 + (l & 7);

    const float* Rb = Rmat + b * 9;       // wave-uniform -> scalar loads
    float R0 = Rb[0], R1 = Rb[1], R2 = Rb[2];
    float R3 = Rb[3], R4 = Rb[4], R5 = Rb[5];
    float R6 = Rb[6], R7 = Rb[7], R8 = Rb[8];

    const float c = (DVOX - 1) * 0.5f;    // 31.5
    float di = (float)i - c, dj = (float)j - c;
    float xb = fmaf(R0, di, fmaf(R1, dj, c));
    float yb = fmaf(R3, di, fmaf(R4, dj, c));
    float zb = fmaf(R6, di, fmaf(R7, dj, c));

    // tile-center pixel offsets (wave-uniform)
    float dic = (float)i0 + 3.5f - c;
    float djc = (float)j0 + 3.5f - c;
    float hwx = 3.5f * (fabsf(R0) + fabsf(R1) + fabsf(R2)) + 1e-3f;
    float hwy = 3.5f * (fabsf(R3) + fabsf(R4) + fabsf(R5)) + 1e-3f;
    float hwz = 3.5f * (fabsf(R6) + fabsf(R7) + fabsf(R8)) + 1e-3f;

    const unsigned short* V = (const unsigned short*)(vox + (size_t)b * VOX);

    float img = 0.f;
    for (int ch = 7; ch >= 0; --ch) {     // back-to-front chunks
        int k0 = ch * 8;
        float dkc = (float)k0 + 3.5f - c;
        // chunk bbox lows (wave-uniform)
        float xc = fmaf(R0, dic, fmaf(R1, djc, fmaf(R2, dkc, c)));
        float yc = fmaf(R3, dic, fmaf(R4, djc, fmaf(R5, dkc, c)));
        float zc = fmaf(R6, dic, fmaf(R7, djc, fmaf(R8, dkc, c)));
        int xlo = (int)floorf(xc - hwx);
        int ylo = (int)floorf(yc - hwy);
        int zlo = (int)floorf(zc - hwz);

        __syncthreads();                  // prev chunk's reads done
        // stage 16x16x16 brick: 4096 entries / 64 lanes = 64 iters
#pragma unroll 4
        for (int it = 0; it < 64; ++it) {
            int e = it * 64 + l;
            int x = e >> 8, y = (e >> 4) & 15, z = e & 15;
            int gx = xlo + x, gy = ylo + y, gz = zlo + z;
            unsigned lo = 0, hi = 0;
            if (((unsigned)gx < (unsigned)DVOX) & ((unsigned)gy < (unsigned)DVOX)) {
                int base = (gx << 12) + (gy << 6);
                if ((unsigned)gz < (unsigned)DVOX)       lo = V[base + gz];
                if ((unsigned)(gz + 1) < (unsigned)DVOX) hi = V[base + gz + 1];
            }
            sV[e] = lo | (hi << 16);
        }
        __syncthreads();

#pragma unroll
        for (int kk = 7; kk >= 0; --kk) { // back-to-front within chunk
            float dk = (float)(k0 + kk) - c;
            float x = fmaf(R2, dk, xb);
            float y = fmaf(R5, dk, yb);
            float z = fmaf(R8, dk, zb);

            float xf = floorf(x), yf = floorf(y), zf = floorf(z);
            float fx = x - xf, fy = y - yf, fz = z - zf;
            int xi = (int)xf - xlo;       // in [0,14]
            int yi = (int)yf - ylo;
            int zi = (int)zf - zlo;
            int idx = (xi << 8) | (yi << 4) | zi;

            unsigned e00 = sV[idx];           // (x0,y0): z-pair
            unsigned e01 = sV[idx + 16];      // (x0,y1)
            unsigned e10 = sV[idx + 256];     // (x1,y0)
            unsigned e11 = sV[idx + 272];     // (x1,y1)

            float c00 = zlerp(e00, fz);
            float c01 = zlerp(e01, fz);
            float c10 = zlerp(e10, fz);
            float c11 = zlerp(e11, fz);
            float c0 = c00 + (c01 - c00) * fy;
            float c1 = c10 + (c11 - c10) * fy;
            float a  = c0  + (c1  - c0 ) * fx;

            img = img * (1.f - a) + a;
        }
    }

    out[b * (DVOX * DVOX) + i * DVOX + j] = 2.f * img - 1.f;
}

// ---------------------------------------------------------------------------
extern "C" void kernel_launch(void* const* d_in, const int* in_sizes, int n_in,
                              void* d_out, int out_size, void* d_ws, size_t ws_size,
                              hipStream_t stream) {
    const float* enc    = (const float*)d_in[0];
    const float* W      = (const float*)d_in[1];
    const float* bias   = (const float*)d_in[2];
    const float* angles = (const float*)d_in[3];
    float* out = (float*)d_out;

    char* ws = (char*)d_ws;
    unsigned short* encB = (unsigned short*)ws;           // 32 KB
    float* Rmat          = (float*)(ws + 32768);          // 2.3 KB
    __half* vox          = (__half*)(ws + 65536);         // 32 MiB

    prep_kernel<<<1, 256, 0, stream>>>(enc, angles, encB, Rmat);
    gemm_mfma_kernel<<<VOX / 64, 256, 0, stream>>>(encB, W, bias, vox);
    render_lds_kernel<<<BATCH * 64, 64, 0, stream>>>(vox, Rmat, out);
}

// Round 5
// 167.575 us; speedup vs baseline: 2.5256x; 2.1227x over previous
//
#include <hip/hip_runtime.h>
#include <hip/hip_bf16.h>
#include <hip/hip_fp16.h>
#include <math.h>

#define BATCH 64
#define LAT   256
#define DVOX  64
#define VOX   (DVOX*DVOX*DVOX)   // 262144

typedef __attribute__((ext_vector_type(8))) short short8;
typedef __attribute__((ext_vector_type(4))) float f32x4;

// ---------------- kernel 0: enc -> bf16, build rotation matrices -----------
__global__ void prep_kernel(const float* __restrict__ enc,      // [64,256]
                            const float* __restrict__ angles,   // [64,3]
                            unsigned short* __restrict__ encB,  // [64,256] bf16 bits
                            float* __restrict__ Rmat) {         // [64,9]
    int tid = threadIdx.x;
    for (int idx = tid; idx < BATCH * LAT; idx += blockDim.x) {
        __hip_bfloat16 h = __float2bfloat16(enc[idx]);
        encB[idx] = *reinterpret_cast<unsigned short*>(&h);
    }
    if (tid < BATCH) {
        float ax = angles[tid*3+0], ay = angles[tid*3+1], az = angles[tid*3+2];
        float cx = cosf(ax), sx = sinf(ax);
        float cy = cosf(ay), sy = sinf(ay);
        float cz = cosf(az), sz = sinf(az);
        float* R = Rmat + tid * 9;
        R[0] = cz*cy;  R[1] = cz*sy*sx - sz*cx;  R[2] = cz*sy*cx + sz*sx;
        R[3] = sz*cy;  R[4] = sz*sy*sx + cz*cx;  R[5] = sz*sy*cx - cz*sx;
        R[6] = -sy;    R[7] = cy*sx;             R[8] = cy*cx;
    }
}

// ---------------- kernel 1: MFMA GEMM + sigmoid^8 -> fp16 voxels -----------
// Two 16-col n-tiles per wave (16 W dwords in flight per k-step) + 2-stage
// software pipeline (next k-block's A and W loads issued before MFMAs).
__global__ __launch_bounds__(256) void gemm_mfma_kernel(
        const unsigned short* __restrict__ encB,  // [64,256] bf16
        const float* __restrict__ W,              // [256, 262144]
        const float* __restrict__ bias,           // [262144]
        __half* __restrict__ vox) {               // [64, 262144] fp16
    int wave = threadIdx.x >> 6;
    int lane = threadIdx.x & 63;
    int l15 = lane & 15, l4 = lane >> 4;
    int nA = blockIdx.x * 128 + wave * 32 + l15;   // second tile at +16

    f32x4 acc[2][4];
#pragma unroll
    for (int t = 0; t < 2; ++t)
#pragma unroll
        for (int mt = 0; mt < 4; ++mt) acc[t][mt] = (f32x4){0.f, 0.f, 0.f, 0.f};

    const unsigned short* ap = encB + l15 * LAT + l4 * 8;
    const float* wp = W + (size_t)(l4 * 8) * VOX + nA;

    short8 a_c[4], a_n[4];
    float wc[16], wn[16];

#pragma unroll
    for (int mt = 0; mt < 4; ++mt) a_c[mt] = *(const short8*)(ap + mt * 16 * LAT);
#pragma unroll
    for (int j = 0; j < 8; ++j) {
        const float* w = wp + (size_t)j * VOX;
        wc[j] = w[0]; wc[8 + j] = w[16];
    }

#pragma unroll
    for (int kb = 0; kb < LAT; kb += 32) {
        if (kb + 32 < LAT) {
#pragma unroll
            for (int mt = 0; mt < 4; ++mt)
                a_n[mt] = *(const short8*)(ap + mt * 16 * LAT + kb + 32);
            const float* wpn = wp + (size_t)(kb + 32) * VOX;
#pragma unroll
            for (int j = 0; j < 8; ++j) {
                const float* w = wpn + (size_t)j * VOX;
                wn[j] = w[0]; wn[8 + j] = w[16];
            }
        }
        short8 bA, bB;
#pragma unroll
        for (int j = 0; j < 8; ++j) {
            __hip_bfloat16 h = __float2bfloat16(wc[j]);
            bA[j] = *reinterpret_cast<short*>(&h);
            __hip_bfloat16 g = __float2bfloat16(wc[8 + j]);
            bB[j] = *reinterpret_cast<short*>(&g);
        }
#pragma unroll
        for (int mt = 0; mt < 4; ++mt) {
            acc[0][mt] = __builtin_amdgcn_mfma_f32_16x16x32_bf16(a_c[mt], bA, acc[0][mt], 0, 0, 0);
            acc[1][mt] = __builtin_amdgcn_mfma_f32_16x16x32_bf16(a_c[mt], bB, acc[1][mt], 0, 0, 0);
        }
#pragma unroll
        for (int mt = 0; mt < 4; ++mt) a_c[mt] = a_n[mt];
#pragma unroll
        for (int j = 0; j < 16; ++j) wc[j] = wn[j];
    }

#pragma unroll
    for (int t = 0; t < 2; ++t) {
        int n = nA + t * 16;
        float bv = bias[n];
#pragma unroll
        for (int mt = 0; mt < 4; ++mt) {
#pragma unroll
            for (int r = 0; r < 4; ++r) {
                int b = mt * 16 + l4 * 4 + r;
                float x = acc[t][mt][r] + bv;
                float s = 1.f / (1.f + __expf(-x));   // sigmoid
                s = s * s; s = s * s; s = s * s;      // ^8
                vox[(size_t)b * VOX + n] = __float2half(s);
            }
        }
    }
}

// ---------------- kernel 2: LDS-staged rotate-resample + composite ---------
// Brick: 16x16x16 entries, entry(x,y,z) = (V[z],V[z+1]) fp16 pair, row stride
// 17 dwords (2-way bank aliasing on staging writes = free; sample reads at
// immediate byte offsets +68/+1088/+1156). Staging per row: 9 unconditional
// aligned dword loads (clamped addr), per-lane x/y mask, wave-uniform z masks,
// 8 alignbit packs, 16 dword LDS writes. No branches in the hot path.
__device__ __forceinline__ float zlerp(unsigned e, float fz) {
    __half2 h = *reinterpret_cast<__half2*>(&e);
    float2 f = __half22float2(h);
    return f.x + (f.y - f.x) * fz;
}

__global__ __launch_bounds__(64) void render_lds_kernel(
        const __half* __restrict__ vox,   // [64, 262144] fp16
        const float* __restrict__ Rmat,   // [64,9]
        float* __restrict__ out) {        // [64,1,64,64]
    __shared__ unsigned sV[16 * 16 * 17];  // 17408 B

    int bid  = blockIdx.x;
    int b    = bid & 63;                  // bid%8 == b%8 -> XCD affinity
    int tile = bid >> 6;
    int l    = threadIdx.x;
    int i0 = (tile >> 3) * 8, j0 = (tile & 7) * 8;
    int i = i0 + (l >> 3);
    int j = j0 + (l & 7);

    const float* Rb = Rmat + b * 9;       // wave-uniform -> scalar loads
    float R0 = Rb[0], R1 = Rb[1], R2 = Rb[2];
    float R3 = Rb[3], R4 = Rb[4], R5 = Rb[5];
    float R6 = Rb[6], R7 = Rb[7], R8 = Rb[8];

    const float c = (DVOX - 1) * 0.5f;    // 31.5
    float di = (float)i - c, dj = (float)j - c;
    float xb = fmaf(R0, di, fmaf(R1, dj, c));
    float yb = fmaf(R3, di, fmaf(R4, dj, c));
    float zb = fmaf(R6, di, fmaf(R7, dj, c));

    float dic = (float)i0 + 3.5f - c;     // tile-center offsets (uniform)
    float djc = (float)j0 + 3.5f - c;
    float hwx = 3.5f * (fabsf(R0) + fabsf(R1) + fabsf(R2)) + 1e-3f;
    float hwy = 3.5f * (fabsf(R3) + fabsf(R4) + fabsf(R5)) + 1e-3f;
    float hwz = 3.5f * (fabsf(R6) + fabsf(R7) + fabsf(R8)) + 1e-3f;

    const unsigned short* V = (const unsigned short*)vox + (size_t)b * VOX;

    float img = 0.f;
    for (int ch = 7; ch >= 0; --ch) {     // back-to-front chunks of 8 z
        int k0 = ch * 8;
        float dkc = (float)k0 + 3.5f - c;
        float xc = fmaf(R0, dic, fmaf(R1, djc, fmaf(R2, dkc, c)));
        float yc = fmaf(R3, dic, fmaf(R4, djc, fmaf(R5, dkc, c)));
        float zc = fmaf(R6, dic, fmaf(R7, djc, fmaf(R8, dkc, c)));
        int xlo = (int)floorf(xc - hwx);
        int ylo = (int)floorf(yc - hwy);
        int zlo = (int)floorf(zc - hwz);

        int  s    = zlo & ~1;             // even half-index start (uniform)
        bool zint = (zlo >= 0) && (zlo + 17 <= 64);

        __syncthreads();                  // prev chunk's reads done
#pragma unroll
        for (int it = 0; it < 4; ++it) {
            int row = it * 64 + l;        // 256 rows: x=row>>4, y=row&15
            int x = row >> 4, y = row & 15;
            int gx = xlo + x, gy = ylo + y;
            bool rv = ((unsigned)gx < (unsigned)DVOX) &
                      ((unsigned)gy < (unsigned)DVOX);
            int gxc = min(max(gx, 0), DVOX - 1);
            int gyc = min(max(gy, 0), DVOX - 1);
            const unsigned* p = (const unsigned*)(V + ((gxc << 12) + (gyc << 6) + s));

            unsigned d[9];
#pragma unroll
            for (int k = 0; k < 9; ++k) d[k] = p[k];   // 4B-aligned, in-ws
            if (!zint) {                  // wave-uniform branch
#pragma unroll
                for (int k = 0; k < 9; ++k) {
                    int h0 = s + 2 * k;
                    unsigned m = (((unsigned)h0 < (unsigned)DVOX) ? 0x0000FFFFu : 0u)
                               | (((unsigned)(h0 + 1) < (unsigned)DVOX) ? 0xFFFF0000u : 0u);
                    d[k] &= m;
                }
            }
            unsigned rvm = rv ? 0xFFFFFFFFu : 0u;
#pragma unroll
            for (int k = 0; k < 9; ++k) d[k] &= rvm;

            unsigned A[8];
#pragma unroll
            for (int m = 0; m < 8; ++m)
                A[m] = (d[m] >> 16) | (d[m + 1] << 16);   // v_alignbit

            unsigned* wrow = sV + row * 17;
            if (zlo & 1) {                // wave-uniform
#pragma unroll
                for (int m = 0; m < 8; ++m) {
                    wrow[2 * m]     = A[m];
                    wrow[2 * m + 1] = d[m + 1];
                }
            } else {
#pragma unroll
                for (int m = 0; m < 8; ++m) {
                    wrow[2 * m]     = d[m];
                    wrow[2 * m + 1] = A[m];
                }
            }
        }
        __syncthreads();

#pragma unroll
        for (int kk = 7; kk >= 0; --kk) { // back-to-front within chunk
            float dk = (float)(k0 + kk) - c;
            float x = fmaf(R2, dk, xb);
            float y = fmaf(R5, dk, yb);
            float z = fmaf(R8, dk, zb);

            float xf = floorf(x), yf = floorf(y), zf = floorf(z);
            float fx = x - xf, fy = y - yf, fz = z - zf;
            int xi = (int)xf - xlo;       // [0,14]
            int yi = (int)yf - ylo;
            int zi = (int)zf - zlo;
            const unsigned* e = sV + (xi * 272 + yi * 17 + zi);

            float c00 = zlerp(e[0],   fz);   // (x0,y0)
            float c01 = zlerp(e[17],  fz);   // (x0,y1)
            float c10 = zlerp(e[272], fz);   // (x1,y0)
            float c11 = zlerp(e[289], fz);   // (x1,y1)
            float c0 = c00 + (c01 - c00) * fy;
            float c1 = c10 + (c11 - c10) * fy;
            float a  = c0  + (c1  - c0 ) * fx;

            img = img * (1.f - a) + a;
        }
    }

    out[b * (DVOX * DVOX) + i * DVOX + j] = 2.f * img - 1.f;
}

// ---------------------------------------------------------------------------
extern "C" void kernel_launch(void* const* d_in, const int* in_sizes, int n_in,
                              void* d_out, int out_size, void* d_ws, size_t ws_size,
                              hipStream_t stream) {
    const float* enc    = (const float*)d_in[0];
    const float* W      = (const float*)d_in[1];
    const float* bias   = (const float*)d_in[2];
    const float* angles = (const float*)d_in[3];
    float* out = (float*)d_out;

    char* ws = (char*)d_ws;
    unsigned short* encB = (unsigned short*)ws;           // 32 KB
    float* Rmat          = (float*)(ws + 32768);          // 2.3 KB
    __half* vox          = (__half*)(ws + 65536);         // 32 MiB

    prep_kernel<<<1, 256, 0, stream>>>(enc, angles, encB, Rmat);
    gemm_mfma_kernel<<<VOX / 128, 256, 0, stream>>>(encB, W, bias, vox);
    render_lds_kernel<<<BATCH * 64, 64, 0, stream>>>(vox, Rmat, out);
}

// Round 6
// 160.987 us; speedup vs baseline: 2.6289x; 1.0409x over previous
//
#include <hip/hip_runtime.h>
#include <hip/hip_bf16.h>
#include <hip/hip_fp16.h>
#include <math.h>

#define BATCH 64
#define LAT   256
#define DVOX  64
#define VOX   (DVOX*DVOX*DVOX)   // 262144

typedef __attribute__((ext_vector_type(8))) short short8;
typedef __attribute__((ext_vector_type(4))) float f32x4;

// ---------------- kernel 0: enc -> bf16, build rotation matrices -----------
__global__ void prep_kernel(const float* __restrict__ enc,      // [64,256]
                            const float* __restrict__ angles,   // [64,3]
                            unsigned short* __restrict__ encB,  // [64,256] bf16 bits
                            float* __restrict__ Rmat) {         // [64,9]
    int tid = threadIdx.x;
    for (int idx = tid; idx < BATCH * LAT; idx += blockDim.x) {
        __hip_bfloat16 h = __float2bfloat16(enc[idx]);
        encB[idx] = *reinterpret_cast<unsigned short*>(&h);
    }
    if (tid < BATCH) {
        float ax = angles[tid*3+0], ay = angles[tid*3+1], az = angles[tid*3+2];
        float cx = cosf(ax), sx = sinf(ax);
        float cy = cosf(ay), sy = sinf(ay);
        float cz = cosf(az), sz = sinf(az);
        float* R = Rmat + tid * 9;
        R[0] = cz*cy;  R[1] = cz*sy*sx - sz*cx;  R[2] = cz*sy*cx + sz*sx;
        R[3] = sz*cy;  R[4] = sz*sy*sx + cz*cx;  R[5] = sz*sy*cx - cz*sx;
        R[6] = -sy;    R[7] = cy*sx;             R[8] = cy*cx;
    }
}

// ---------------- kernel 1: MFMA GEMM + sigmoid^8 -> fp16 voxels -----------
// 32-col span per wave as two INTERLEAVED 16-col tiles (tile0 = even cols,
// tile1 = odd cols): one float2 load per (lane, k-row) feeds both B-frags
// (global_load_dwordx2, 8 per k-step), and the epilogue fuses the two accs
// into one __half2 dword store. 2-stage software pipeline over k-blocks.
__global__ __launch_bounds__(256) void gemm_mfma_kernel(
        const unsigned short* __restrict__ encB,  // [64,256] bf16
        const float* __restrict__ W,              // [256, 262144]
        const float* __restrict__ bias,           // [262144]
        __half* __restrict__ vox) {               // [64, 262144] fp16
    int wave = threadIdx.x >> 6;
    int lane = threadIdx.x & 63;
    int l15 = lane & 15, l4 = lane >> 4;
    int n2 = blockIdx.x * 128 + wave * 32 + 2 * l15;   // even col of this lane

    f32x4 acc[2][4];
#pragma unroll
    for (int t = 0; t < 2; ++t)
#pragma unroll
        for (int mt = 0; mt < 4; ++mt) acc[t][mt] = (f32x4){0.f, 0.f, 0.f, 0.f};

    const unsigned short* ap = encB + l15 * LAT + l4 * 8;
    const float* wp = W + (size_t)(l4 * 8) * VOX + n2;

    short8 a_c[4], a_n[4];
    float2 wc[8], wn[8];

#pragma unroll
    for (int mt = 0; mt < 4; ++mt) a_c[mt] = *(const short8*)(ap + mt * 16 * LAT);
#pragma unroll
    for (int j = 0; j < 8; ++j)
        wc[j] = *(const float2*)(wp + (size_t)j * VOX);

#pragma unroll
    for (int kb = 0; kb < LAT; kb += 32) {
        if (kb + 32 < LAT) {
#pragma unroll
            for (int mt = 0; mt < 4; ++mt)
                a_n[mt] = *(const short8*)(ap + mt * 16 * LAT + kb + 32);
            const float* wpn = wp + (size_t)(kb + 32) * VOX;
#pragma unroll
            for (int j = 0; j < 8; ++j)
                wn[j] = *(const float2*)(wpn + (size_t)j * VOX);
        }
        short8 bA, bB;
#pragma unroll
        for (int j = 0; j < 8; ++j) {
            __hip_bfloat16 h = __float2bfloat16(wc[j].x);
            bA[j] = *reinterpret_cast<short*>(&h);
            __hip_bfloat16 g = __float2bfloat16(wc[j].y);
            bB[j] = *reinterpret_cast<short*>(&g);
        }
#pragma unroll
        for (int mt = 0; mt < 4; ++mt) {
            acc[0][mt] = __builtin_amdgcn_mfma_f32_16x16x32_bf16(a_c[mt], bA, acc[0][mt], 0, 0, 0);
            acc[1][mt] = __builtin_amdgcn_mfma_f32_16x16x32_bf16(a_c[mt], bB, acc[1][mt], 0, 0, 0);
        }
#pragma unroll
        for (int mt = 0; mt < 4; ++mt) a_c[mt] = a_n[mt];
#pragma unroll
        for (int j = 0; j < 8; ++j) wc[j] = wn[j];
    }

    float2 bv = *(const float2*)(bias + n2);
#pragma unroll
    for (int mt = 0; mt < 4; ++mt) {
#pragma unroll
        for (int r = 0; r < 4; ++r) {
            int b = mt * 16 + l4 * 4 + r;
            float x0 = acc[0][mt][r] + bv.x;
            float x1 = acc[1][mt][r] + bv.y;
            float s0 = 1.f / (1.f + __expf(-x0));
            float s1 = 1.f / (1.f + __expf(-x1));
            s0 = s0 * s0; s0 = s0 * s0; s0 = s0 * s0;   // ^8
            s1 = s1 * s1; s1 = s1 * s1; s1 = s1 * s1;
            *reinterpret_cast<__half2*>(vox + (size_t)b * VOX + n2) =
                __floats2half2_rn(s0, s1);
        }
    }
}

// ---------------- kernel 2: pipelined LDS-staged resample + composite ------
// Brick: 16x16x16 entries (z-pair dwords), row stride 17. Cross-chunk
// software pipeline: regs d[4][9] hold the NEXT chunk's 36 staged dwords;
// per chunk: pack regs->LDS, issue next chunk's loads, then sample — load
// latency hides under the sample loop.
__device__ __forceinline__ float zlerp(unsigned e, float fz) {
    __half2 h = *reinterpret_cast<__half2*>(&e);
    float2 f = __half22float2(h);
    return f.x + (f.y - f.x) * fz;
}

__global__ __launch_bounds__(64) void render_lds_kernel(
        const __half* __restrict__ vox,   // [64, 262144] fp16
        const float* __restrict__ Rmat,   // [64,9]
        float* __restrict__ out) {        // [64,1,64,64]
    __shared__ unsigned sV[16 * 16 * 17];  // 17408 B

    int bid  = blockIdx.x;
    int b    = bid & 63;                  // bid%8 == b%8 -> XCD affinity
    int tile = bid >> 6;
    int l    = threadIdx.x;
    int i0 = (tile >> 3) * 8, j0 = (tile & 7) * 8;
    int i = i0 + (l >> 3);
    int j = j0 + (l & 7);

    const float* Rb = Rmat + b * 9;       // wave-uniform -> scalar loads
    float R0 = Rb[0], R1 = Rb[1], R2 = Rb[2];
    float R3 = Rb[3], R4 = Rb[4], R5 = Rb[5];
    float R6 = Rb[6], R7 = Rb[7], R8 = Rb[8];

    const float c = (DVOX - 1) * 0.5f;    // 31.5
    float di = (float)i - c, dj = (float)j - c;
    float xb = fmaf(R0, di, fmaf(R1, dj, c));
    float yb = fmaf(R3, di, fmaf(R4, dj, c));
    float zb = fmaf(R6, di, fmaf(R7, dj, c));

    float dic = (float)i0 + 3.5f - c;     // tile-center offsets (uniform)
    float djc = (float)j0 + 3.5f - c;
    float hwx = 3.5f * (fabsf(R0) + fabsf(R1) + fabsf(R2)) + 1e-3f;
    float hwy = 3.5f * (fabsf(R3) + fabsf(R4) + fabsf(R5)) + 1e-3f;
    float hwz = 3.5f * (fabsf(R6) + fabsf(R7) + fabsf(R8)) + 1e-3f;

    const unsigned short* V = (const unsigned short*)vox + (size_t)b * VOX;

    unsigned d[4][9];                     // staged loads for chunk "_n"
    int xlo_n, ylo_n, zlo_n, s_n;

    auto bbox = [&](int ch) {
        float dkc = (float)(ch * 8) + 3.5f - c;
        float xc = fmaf(R0, dic, fmaf(R1, djc, fmaf(R2, dkc, c)));
        float yc = fmaf(R3, dic, fmaf(R4, djc, fmaf(R5, dkc, c)));
        float zc = fmaf(R6, dic, fmaf(R7, djc, fmaf(R8, dkc, c)));
        xlo_n = (int)floorf(xc - hwx);
        ylo_n = (int)floorf(yc - hwy);
        zlo_n = (int)floorf(zc - hwz);
        s_n   = zlo_n & ~1;
    };
    auto issue = [&]() {
#pragma unroll
        for (int it = 0; it < 4; ++it) {
            int row = it * 64 + l;
            int x = row >> 4, y = row & 15;
            int gxc = min(max(xlo_n + x, 0), DVOX - 1);
            int gyc = min(max(ylo_n + y, 0), DVOX - 1);
            const unsigned* p = (const unsigned*)(V + ((gxc << 12) + (gyc << 6) + s_n));
#pragma unroll
            for (int k = 0; k < 9; ++k) d[it][k] = p[k];
        }
    };

    bbox(7); issue();
    int xlo = xlo_n, ylo = ylo_n, zlo = zlo_n, s = s_n;

    float img = 0.f;
#pragma unroll 1
    for (int ch = 7; ch >= 0; --ch) {     // back-to-front chunks of 8 z
        bool zint = (zlo >= 0) && (zlo + 17 <= DVOX);

        __syncthreads();                  // prev chunk's LDS reads done
        // ---- pack regs -> LDS (masks + alignbit), branch-free per lane ----
#pragma unroll
        for (int it = 0; it < 4; ++it) {
            int row = it * 64 + l;
            int x = row >> 4, y = row & 15;
            bool rv = ((unsigned)(xlo + x) < (unsigned)DVOX) &
                      ((unsigned)(ylo + y) < (unsigned)DVOX);
            unsigned t[9];
#pragma unroll
            for (int k = 0; k < 9; ++k) t[k] = d[it][k];
            if (!zint) {                  // wave-uniform branch
#pragma unroll
                for (int k = 0; k < 9; ++k) {
                    int h0 = s + 2 * k;
                    unsigned m = (((unsigned)h0 < (unsigned)DVOX) ? 0x0000FFFFu : 0u)
                               | (((unsigned)(h0 + 1) < (unsigned)DVOX) ? 0xFFFF0000u : 0u);
                    t[k] &= m;
                }
            }
            unsigned rvm = rv ? 0xFFFFFFFFu : 0u;
#pragma unroll
            for (int k = 0; k < 9; ++k) t[k] &= rvm;

            unsigned A[8];
#pragma unroll
            for (int m = 0; m < 8; ++m)
                A[m] = (t[m] >> 16) | (t[m + 1] << 16);   // v_alignbit

            unsigned* wrow = sV + row * 17;
            if (zlo & 1) {                // wave-uniform
#pragma unroll
                for (int m = 0; m < 8; ++m) {
                    wrow[2 * m]     = A[m];
                    wrow[2 * m + 1] = t[m + 1];
                }
            } else {
#pragma unroll
                for (int m = 0; m < 8; ++m) {
                    wrow[2 * m]     = t[m];
                    wrow[2 * m + 1] = A[m];
                }
            }
        }
        __syncthreads();

        // ---- issue NEXT chunk's loads; latency hides under sampling -------
        if (ch > 0) { bbox(ch - 1); issue(); }

        // ---- sample 8 z-steps from LDS, composite back-to-front -----------
        int k0 = ch * 8;
#pragma unroll
        for (int kk = 7; kk >= 0; --kk) {
            float dk = (float)(k0 + kk) - c;
            float x = fmaf(R2, dk, xb);
            float y = fmaf(R5, dk, yb);
            float z = fmaf(R8, dk, zb);

            float xf = floorf(x), yf = floorf(y), zf = floorf(z);
            float fx = x - xf, fy = y - yf, fz = z - zf;
            int xi = (int)xf - xlo;       // [0,14]
            int yi = (int)yf - ylo;
            int zi = (int)zf - zlo;
            const unsigned* e = sV + (xi * 272 + yi * 17 + zi);

            float c00 = zlerp(e[0],   fz);   // (x0,y0)
            float c01 = zlerp(e[17],  fz);   // (x0,y1)
            float c10 = zlerp(e[272], fz);   // (x1,y0)
            float c11 = zlerp(e[289], fz);   // (x1,y1)
            float c0 = c00 + (c01 - c00) * fy;
            float c1 = c10 + (c11 - c10) * fy;
            float a  = c0  + (c1  - c0 ) * fx;

            img = img * (1.f - a) + a;
        }

        xlo = xlo_n; ylo = ylo_n; zlo = zlo_n; s = s_n;
    }

    out[b * (DVOX * DVOX) + i * DVOX + j] = 2.f * img - 1.f;
}

// ---------------------------------------------------------------------------
extern "C" void kernel_launch(void* const* d_in, const int* in_sizes, int n_in,
                              void* d_out, int out_size, void* d_ws, size_t ws_size,
                              hipStream_t stream) {
    const float* enc    = (const float*)d_in[0];
    const float* W      = (const float*)d_in[1];
    const float* bias   = (const float*)d_in[2];
    const float* angles = (const float*)d_in[3];
    float* out = (float*)d_out;

    char* ws = (char*)d_ws;
    unsigned short* encB = (unsigned short*)ws;           // 32 KB
    float* Rmat          = (float*)(ws + 32768);          // 2.3 KB
    __half* vox          = (__half*)(ws + 65536);         // 32 MiB

    prep_kernel<<<1, 256, 0, stream>>>(enc, angles, encB, Rmat);
    gemm_mfma_kernel<<<VOX / 128, 256, 0, stream>>>(encB, W, bias, vox);
    render_lds_kernel<<<BATCH * 64, 64, 0, stream>>>(vox, Rmat, out);
}

// Round 7
// 142.982 us; speedup vs baseline: 2.9600x; 1.1259x over previous
//
#include <hip/hip_runtime.h>
#include <hip/hip_bf16.h>
#include <hip/hip_fp16.h>
#include <math.h>

#define BATCH 64
#define LAT   256
#define DVOX  64
#define VOX   (DVOX*DVOX*DVOX)   // 262144

typedef __attribute__((ext_vector_type(8))) short short8;
typedef __attribute__((ext_vector_type(4))) float f32x4;

// ---------------- kernel 0: enc -> bf16, build rotation matrices -----------
__global__ void prep_kernel(const float* __restrict__ enc,      // [64,256]
                            const float* __restrict__ angles,   // [64,3]
                            unsigned short* __restrict__ encB,  // [64,256] bf16 bits
                            float* __restrict__ Rmat) {         // [64,9]
    int tid = threadIdx.x;
    for (int idx = tid; idx < BATCH * LAT; idx += blockDim.x) {
        __hip_bfloat16 h = __float2bfloat16(enc[idx]);
        encB[idx] = *reinterpret_cast<unsigned short*>(&h);
    }
    if (tid < BATCH) {
        float ax = angles[tid*3+0], ay = angles[tid*3+1], az = angles[tid*3+2];
        float cx = cosf(ax), sx = sinf(ax);
        float cy = cosf(ay), sy = sinf(ay);
        float cz = cosf(az), sz = sinf(az);
        float* R = Rmat + tid * 9;
        R[0] = cz*cy;  R[1] = cz*sy*sx - sz*cx;  R[2] = cz*sy*cx + sz*sx;
        R[3] = sz*cy;  R[4] = sz*sy*sx + cz*cx;  R[5] = sz*sy*cx - cz*sx;
        R[6] = -sy;    R[7] = cy*sx;             R[8] = cy*cx;
    }
}

// ---------------- kernel 1: MFMA GEMM + sigmoid^8 -> fp16 voxels -----------
// 64-col span per wave as FOUR interleaved 16-col tiles (tile t = cols ≡ t
// mod 4): one float4 W-load per (lane, k-row) feeds all 4 B-frags
// (global_load_dwordx4, 8 per k-step). Epilogue: 4 cols -> one 8B store.
// A-frags reloaded per k-step from L2-hot encB; W prefetched 1 k-block ahead.
__global__ __launch_bounds__(256, 2) void gemm_mfma_kernel(
        const unsigned short* __restrict__ encB,  // [64,256] bf16
        const float* __restrict__ W,              // [256, 262144]
        const float* __restrict__ bias,           // [262144]
        __half* __restrict__ vox) {               // [64, 262144] fp16
    int wave = threadIdx.x >> 6;
    int lane = threadIdx.x & 63;
    int l15 = lane & 15, l4 = lane >> 4;
    int n4 = blockIdx.x * 256 + wave * 64 + 4 * l15;  // cols n4..n4+3

    f32x4 acc[4][4];   // [tile][mt]
#pragma unroll
    for (int t = 0; t < 4; ++t)
#pragma unroll
        for (int mt = 0; mt < 4; ++mt) acc[t][mt] = (f32x4){0.f, 0.f, 0.f, 0.f};

    const unsigned short* ap = encB + l15 * LAT + l4 * 8;
    const float* wp = W + (size_t)(l4 * 8) * VOX + n4;

    float4 wc[8], wn[8];
#pragma unroll
    for (int j = 0; j < 8; ++j)
        wc[j] = *(const float4*)(wp + (size_t)j * VOX);

#pragma unroll
    for (int kb = 0; kb < LAT; kb += 32) {
        if (kb + 32 < LAT) {
            const float* wpn = wp + (size_t)(kb + 32) * VOX;
#pragma unroll
            for (int j = 0; j < 8; ++j)
                wn[j] = *(const float4*)(wpn + (size_t)j * VOX);
        }
        short8 a[4];
#pragma unroll
        for (int mt = 0; mt < 4; ++mt)
            a[mt] = *(const short8*)(ap + mt * 16 * LAT + kb);

        short8 bf[4];
#pragma unroll
        for (int t = 0; t < 4; ++t) {
#pragma unroll
            for (int dw = 0; dw < 4; ++dw) {
                __hip_bfloat16 lo = __float2bfloat16(wc[2 * dw][t]);
                __hip_bfloat16 hi = __float2bfloat16(wc[2 * dw + 1][t]);
                bf[t][2 * dw]     = *reinterpret_cast<short*>(&lo);
                bf[t][2 * dw + 1] = *reinterpret_cast<short*>(&hi);
            }
        }
#pragma unroll
        for (int t = 0; t < 4; ++t)
#pragma unroll
            for (int mt = 0; mt < 4; ++mt)
                acc[t][mt] = __builtin_amdgcn_mfma_f32_16x16x32_bf16(a[mt], bf[t], acc[t][mt], 0, 0, 0);
#pragma unroll
        for (int j = 0; j < 8; ++j) wc[j] = wn[j];
    }

    float4 bv = *(const float4*)(bias + n4);
#pragma unroll
    for (int mt = 0; mt < 4; ++mt) {
#pragma unroll
        for (int r = 0; r < 4; ++r) {
            int b = mt * 16 + l4 * 4 + r;
            float s[4];
#pragma unroll
            for (int t = 0; t < 4; ++t) {
                float x = acc[t][mt][r] + ((const float*)&bv)[t];
                float v = 1.f / (1.f + __expf(-x));   // sigmoid
                v = v * v; v = v * v; v = v * v;      // ^8
                s[t] = v;
            }
            __half2 h01 = __floats2half2_rn(s[0], s[1]);
            __half2 h23 = __floats2half2_rn(s[2], s[3]);
            uint2 pk;
            pk.x = *reinterpret_cast<unsigned*>(&h01);
            pk.y = *reinterpret_cast<unsigned*>(&h23);
            *reinterpret_cast<uint2*>(vox + (size_t)b * VOX + n4) = pk;
        }
    }
}

// ---------------- kernel 2: 4-wave cooperative LDS-brick resample ----------
// Block = 256 thr = 4 waves, one 8x8 pixel tile, ONE shared 16^3 brick.
// Per 8-z chunk: stage 1 row/thread (256 rows), wave s samples z-substeps
// {2s, 2s+1} as a segment (E,T); composite op img->E+T*img is associative,
// wave 0 folds 4 segments/pixel from LDS. Cross-chunk pipeline: next chunk's
// 9 dwords/thread issued before sampling. 2 syncs per chunk. 32 waves/CU.
__device__ __forceinline__ float zlerp(unsigned e, float fz) {
    __half2 h = *reinterpret_cast<__half2*>(&e);
    float2 f = __half22float2(h);
    return f.x + (f.y - f.x) * fz;
}

__global__ __launch_bounds__(256) void render_lds_kernel(
        const __half* __restrict__ vox,   // [64, 262144] fp16
        const float* __restrict__ Rmat,   // [64,9]
        float* __restrict__ out) {        // [64,1,64,64]
    __shared__ unsigned sV[16 * 16 * 17]; // 17408 B brick, row stride 17
    __shared__ float sT[4][64], sE[4][64];

    int bid  = blockIdx.x;
    int b    = bid & 63;                  // bid%8 == b%8 -> XCD affinity
    int tile = bid >> 6;
    int t    = threadIdx.x;
    int pix  = t & 63, seg = t >> 6;      // seg == wave id
    int i0 = (tile >> 3) * 8, j0 = (tile & 7) * 8;
    int i = i0 + (pix >> 3);
    int j = j0 + (pix & 7);

    const float* Rb = Rmat + b * 9;       // uniform -> scalar loads
    float R0 = Rb[0], R1 = Rb[1], R2 = Rb[2];
    float R3 = Rb[3], R4 = Rb[4], R5 = Rb[5];
    float R6 = Rb[6], R7 = Rb[7], R8 = Rb[8];

    const float c = (DVOX - 1) * 0.5f;    // 31.5
    float di = (float)i - c, dj = (float)j - c;
    float xb = fmaf(R0, di, fmaf(R1, dj, c));
    float yb = fmaf(R3, di, fmaf(R4, dj, c));
    float zb = fmaf(R6, di, fmaf(R7, dj, c));

    float dic = (float)i0 + 3.5f - c;     // tile-center offsets (uniform)
    float djc = (float)j0 + 3.5f - c;
    float hwx = 3.5f * (fabsf(R0) + fabsf(R1) + fabsf(R2)) + 1e-3f;
    float hwy = 3.5f * (fabsf(R3) + fabsf(R4) + fabsf(R5)) + 1e-3f;
    float hwz = 3.5f * (fabsf(R6) + fabsf(R7) + fabsf(R8)) + 1e-3f;

    const unsigned short* V = (const unsigned short*)vox + (size_t)b * VOX;

    // this thread's staging row: x = t>>4, y = t&15
    int rx = t >> 4, ry = t & 15;
    unsigned d[9];
    int xlo_n, ylo_n, zlo_n, s_n;

    auto bbox = [&](int ch) {
        float dkc = (float)(ch * 8) + 3.5f - c;
        float xc = fmaf(R0, dic, fmaf(R1, djc, fmaf(R2, dkc, c)));
        float yc = fmaf(R3, dic, fmaf(R4, djc, fmaf(R5, dkc, c)));
        float zc = fmaf(R6, dic, fmaf(R7, djc, fmaf(R8, dkc, c)));
        xlo_n = (int)floorf(xc - hwx);
        ylo_n = (int)floorf(yc - hwy);
        zlo_n = (int)floorf(zc - hwz);
        s_n   = zlo_n & ~1;
    };
    auto issue = [&]() {
        int gxc = min(max(xlo_n + rx, 0), DVOX - 1);
        int gyc = min(max(ylo_n + ry, 0), DVOX - 1);
        const unsigned* p = (const unsigned*)(V + ((gxc << 12) + (gyc << 6) + s_n));
#pragma unroll
        for (int k = 0; k < 9; ++k) d[k] = p[k];
    };

    bbox(7); issue();
    int xlo = xlo_n, ylo = ylo_n, zlo = zlo_n, s = s_n;

    float img = 0.f;                      // live in wave 0 only
#pragma unroll 1
    for (int ch = 7; ch >= 0; --ch) {     // back-to-front chunks of 8 z
        bool zint = (zlo >= 0) && (zlo + 17 <= DVOX);

        // ---- pack this thread's row into the brick ------------------------
        {
            bool rv = ((unsigned)(xlo + rx) < (unsigned)DVOX) &
                      ((unsigned)(ylo + ry) < (unsigned)DVOX);
            unsigned tt[9];
#pragma unroll
            for (int k = 0; k < 9; ++k) tt[k] = d[k];
            if (!zint) {                  // block-uniform branch
#pragma unroll
                for (int k = 0; k < 9; ++k) {
                    int h0 = s + 2 * k;
                    unsigned m = (((unsigned)h0 < (unsigned)DVOX) ? 0x0000FFFFu : 0u)
                               | (((unsigned)(h0 + 1) < (unsigned)DVOX) ? 0xFFFF0000u : 0u);
                    tt[k] &= m;
                }
            }
            unsigned rvm = rv ? 0xFFFFFFFFu : 0u;
#pragma unroll
            for (int k = 0; k < 9; ++k) tt[k] &= rvm;

            unsigned A[8];
#pragma unroll
            for (int m = 0; m < 8; ++m)
                A[m] = (tt[m] >> 16) | (tt[m + 1] << 16);   // v_alignbit

            unsigned* wrow = sV + t * 17;
            if (zlo & 1) {                // block-uniform
#pragma unroll
                for (int m = 0; m < 8; ++m) {
                    wrow[2 * m]     = A[m];
                    wrow[2 * m + 1] = tt[m + 1];
                }
            } else {
#pragma unroll
                for (int m = 0; m < 8; ++m) {
                    wrow[2 * m]     = tt[m];
                    wrow[2 * m + 1] = A[m];
                }
            }
        }
        __syncthreads();

        // ---- issue NEXT chunk's loads (latency hides under sampling) ------
        if (ch > 0) { bbox(ch - 1); issue(); }

        // ---- sample this wave's 2-z segment, back-to-front ----------------
        float T = 1.f, E = 0.f;
        int k0 = ch * 8;
#pragma unroll
        for (int q = 1; q >= 0; --q) {    // kk = 2*seg+1, then 2*seg
            int kk = 2 * seg + q;
            float dk = (float)(k0 + kk) - c;
            float x = fmaf(R2, dk, xb);
            float y = fmaf(R5, dk, yb);
            float z = fmaf(R8, dk, zb);

            float xf = floorf(x), yf = floorf(y), zf = floorf(z);
            float fx = x - xf, fy = y - yf, fz = z - zf;
            int xi = (int)xf - xlo;       // [0,14]
            int yi = (int)yf - ylo;
            int zi = (int)zf - zlo;
            const unsigned* e = sV + (xi * 272 + yi * 17 + zi);

            float c00 = zlerp(e[0],   fz);   // (x0,y0)
            float c01 = zlerp(e[17],  fz);   // (x0,y1)
            float c10 = zlerp(e[272], fz);   // (x1,y0)
            float c11 = zlerp(e[289], fz);   // (x1,y1)
            float c0 = c00 + (c01 - c00) * fy;
            float c1 = c10 + (c11 - c10) * fy;
            float a  = c0  + (c1  - c0 ) * fx;

            E = E * (1.f - a) + a;
            T *= (1.f - a);
        }
        sT[seg][pix] = T;
        sE[seg][pix] = E;
        __syncthreads();

        // ---- wave 0 folds the 4 segments (back seg 3 first) ---------------
        if (seg == 0) {
            float im = img;
#pragma unroll
            for (int ss = 3; ss >= 0; --ss)
                im = fmaf(sT[ss][pix], im, sE[ss][pix]);
            img = im;
        }
        // fold's sT/sE reads are ordered before next chunk's sT/sE writes by
        // the pack-side __syncthreads() of the next iteration.

        xlo = xlo_n; ylo = ylo_n; zlo = zlo_n; s = s_n;
    }

    if (seg == 0)
        out[b * (DVOX * DVOX) + i * DVOX + j] = 2.f * img - 1.f;
}

// ---------------------------------------------------------------------------
extern "C" void kernel_launch(void* const* d_in, const int* in_sizes, int n_in,
                              void* d_out, int out_size, void* d_ws, size_t ws_size,
                              hipStream_t stream) {
    const float* enc    = (const float*)d_in[0];
    const float* W      = (const float*)d_in[1];
    const float* bias   = (const float*)d_in[2];
    const float* angles = (const float*)d_in[3];
    float* out = (float*)d_out;

    char* ws = (char*)d_ws;
    unsigned short* encB = (unsigned short*)ws;           // 32 KB
    float* Rmat          = (float*)(ws + 32768);          // 2.3 KB
    __half* vox          = (__half*)(ws + 65536);         // 32 MiB

    prep_kernel<<<1, 256, 0, stream>>>(enc, angles, encB, Rmat);
    gemm_mfma_kernel<<<VOX / 256, 256, 0, stream>>>(encB, W, bias, vox);
    render_lds_kernel<<<BATCH * 64, 256, 0, stream>>>(vox, Rmat, out);
}